// Round 1
// 678.570 us; speedup vs baseline: 1.0179x; 1.0179x over previous
//
#include <hip/hip_runtime.h>

#define B_  64
#define S_  2048
#define H_  512
#define V_  50257
#define NB_ 32
#define L_  64
#define H3_ 1536
#define NBLK_OUT 786

typedef float  f32x4  __attribute__((ext_vector_type(4)));
typedef __bf16 bf16x8 __attribute__((ext_vector_type(8)));

struct alignas(16) U4 { unsigned int x, y, z, w; };

__device__ __forceinline__ unsigned int f2bf_bits(float f) {
  unsigned int u = __float_as_uint(f);
  return (u + 0x7fffu + ((u >> 16) & 1u)) >> 16;  // RNE
}

__device__ __forceinline__ f32x4 ntload4(const float* p) {
  return __builtin_nontemporal_load((const f32x4*)p);
}

__device__ __forceinline__ float wave_sum(float v) {
#pragma unroll
  for (int off = 32; off > 0; off >>= 1) v += __shfl_xor(v, off, 64);
  return v;
}

// q[b,h] = sum_g hidden[1][b,g] * attn_W[g,h]   (64 blocks, 4 b x 128 h each)
__global__ __launch_bounds__(128) void k_q(const float* __restrict__ hidden,
                                           const float* __restrict__ attn_W,
                                           float* __restrict__ q) {
  __shared__ float sh[4 * H_];
  int tid = threadIdx.x;
  int h  = blockIdx.x * 128 + tid;
  int b0 = blockIdx.y * 4;
  const float* h1 = hidden + B_ * H_;
  for (int i = tid; i < 4 * H_; i += 128) sh[i] = h1[b0 * H_ + i];
  __syncthreads();
  float acc[4] = {0.f, 0.f, 0.f, 0.f};
  for (int g = 0; g < H_; ++g) {
    float w = attn_W[(size_t)g * H_ + h];
#pragma unroll
    for (int bb = 0; bb < 4; ++bb) acc[bb] += sh[bb * H_ + g] * w;
  }
#pragma unroll
  for (int bb = 0; bb < 4; ++bb) q[(b0 + bb) * H_ + h] = acc[bb];
}

// One block (8 waves) per (b,n). Wave w handles rows [w*8, w*8+8), 2 rows
// per iteration (4-deep serial softmax chain); merge across 8 waves in LDS.
__global__ __launch_bounds__(512) void k_attn(
    const float* __restrict__ eo, const float* __restrict__ hidden,
    const float* __restrict__ attn_b, const float* __restrict__ q,
    float* __restrict__ bc, float* __restrict__ attnw_out) {
  __shared__ float sm[8], ss[8];
  __shared__ float shA[8][H_];
  int tid = threadIdx.x;
  int wv = tid >> 6, lane = tid & 63;
  int idx = blockIdx.x;
  int b = idx >> 5, n = idx & 31;

  f32x4 q0 = *(const f32x4*)(q + (size_t)b * H_ + lane * 4);
  f32x4 q1 = *(const f32x4*)(q + (size_t)b * H_ + 256 + lane * 4);

  // c0 = dot(hidden[1][b], attn_b)
  const float* hp = hidden + (size_t)B_ * H_ + (size_t)b * H_;
  f32x4 hx = *(const f32x4*)(hp + lane * 4);
  f32x4 hy = *(const f32x4*)(hp + 256 + lane * 4);
  f32x4 ax = *(const f32x4*)(attn_b + lane * 4);
  f32x4 ay = *(const f32x4*)(attn_b + 256 + lane * 4);
  float c0 = hx.x*ax.x + hx.y*ax.y + hx.z*ax.z + hx.w*ax.w
           + hy.x*ay.x + hy.y*ay.y + hy.z*ay.z + hy.w*ay.w;
  c0 = wave_sum(c0);

  const float* eb = eo + (size_t)(b * NB_ + n) * L_ * H_;
  float m = -1e30f, s = 0.f, myscore = 0.f;
  f32x4 A0 = {0,0,0,0}, A1 = {0,0,0,0};
  for (int lr = 0; lr < 8; lr += 2) {
    const float* rA = eb + (size_t)(wv * 8 + lr) * H_;
    const float* rB = rA + H_;
    f32x4 a0 = ntload4(rA + lane * 4);
    f32x4 a1 = ntload4(rA + 256 + lane * 4);
    f32x4 b0 = ntload4(rB + lane * 4);
    f32x4 b1 = ntload4(rB + 256 + lane * 4);
    float pa = a0.x*q0.x + a0.y*q0.y + a0.z*q0.z + a0.w*q0.w
             + a1.x*q1.x + a1.y*q1.y + a1.z*q1.z + a1.w*q1.w;
    float pb = b0.x*q0.x + b0.y*q0.y + b0.z*q0.z + b0.w*q0.w
             + b1.x*q1.x + b1.y*q1.y + b1.z*q1.z + b1.w*q1.w;
#pragma unroll
    for (int off = 32; off > 0; off >>= 1) {
      pa += __shfl_xor(pa, off, 64);
      pb += __shfl_xor(pb, off, 64);
    }
    pa += c0; pb += c0;
    if (lane == lr)     myscore = pa;
    if (lane == lr + 1) myscore = pb;
    float mnew  = fmaxf(m, fmaxf(pa, pb));
    float alpha = __expf(m - mnew);
    float wa    = __expf(pa - mnew);
    float wb    = __expf(pb - mnew);
    s = s * alpha + wa + wb;
    A0.x = A0.x*alpha + wa*a0.x + wb*b0.x;
    A0.y = A0.y*alpha + wa*a0.y + wb*b0.y;
    A0.z = A0.z*alpha + wa*a0.z + wb*b0.z;
    A0.w = A0.w*alpha + wa*a0.w + wb*b0.w;
    A1.x = A1.x*alpha + wa*a1.x + wb*b1.x;
    A1.y = A1.y*alpha + wa*a1.y + wb*b1.y;
    A1.z = A1.z*alpha + wa*a1.z + wb*b1.z;
    A1.w = A1.w*alpha + wa*a1.w + wb*b1.w;
    m = mnew;
  }
  if (lane == 0) { sm[wv] = m; ss[wv] = s; }
  __syncthreads();
  float m_g = sm[0];
#pragma unroll
  for (int w = 1; w < 8; ++w) m_g = fmaxf(m_g, sm[w]);
  float s_g = 0.f;
#pragma unroll
  for (int w = 0; w < 8; ++w) s_g += ss[w] * __expf(sm[w] - m_g);
  float scale = __expf(m - m_g);
  f32x4* pa4 = (f32x4*)&shA[wv][0];
  f32x4 w0 = {A0.x*scale, A0.y*scale, A0.z*scale, A0.w*scale};
  f32x4 w1 = {A1.x*scale, A1.y*scale, A1.z*scale, A1.w*scale};
  pa4[lane] = w0; pa4[64 + lane] = w1;
  __syncthreads();
  float inv = 1.f / s_g;
  float sum = 0.f;
#pragma unroll
  for (int w = 0; w < 8; ++w) sum += shA[w][tid];
  bc[(size_t)(b * NB_ + n) * H_ + tid] = sum * inv;
  if (lane < 8)
    attnw_out[(size_t)(b * NB_ + n) * L_ + wv * 8 + lane] =
        __expf(myscore - m_g) * inv;
}

// context reduce over n, embedding gather, bf16 conversions of x_cat / h0 / h1
__global__ __launch_bounds__(512) void k_prep(
    const int* __restrict__ ids, const float* __restrict__ hidden,
    const float* __restrict__ baw, const float* __restrict__ emb,
    const float* __restrict__ bc, float* __restrict__ ctx,
    unsigned short* __restrict__ xcatb, unsigned short* __restrict__ h0b,
    unsigned short* __restrict__ h1b, float* __restrict__ out_ctx) {
  int b = blockIdx.x, h = threadIdx.x;
  int id = ids[b];
  float ev = emb[(size_t)id * H_ + h];
  float acc = 0.f;
  for (int n = 0; n < NB_; ++n)
    acc += baw[b * NB_ + n] * bc[(size_t)(b * NB_ + n) * H_ + h];
  ctx[b * H_ + h]      = acc;
  out_ctx[b * H_ + h]  = acc;
  xcatb[b * 1024 + h]        = (unsigned short)f2bf_bits(ev);
  xcatb[b * 1024 + 512 + h]  = (unsigned short)f2bf_bits(acc);
  h0b[b * H_ + h] = (unsigned short)f2bf_bits(hidden[b * H_ + h]);
  h1b[b * H_ + h] = (unsigned short)f2bf_bits(hidden[B_ * H_ + b * H_ + h]);
}

// Two fused matvec64 GEMMs (gx and gh): blocks [0,96) do #1, [96,192) do #2.
__global__ __launch_bounds__(256) void k_mv2(
    const float* __restrict__ W1, const float* __restrict__ bias1,
    const unsigned short* __restrict__ A1, float* __restrict__ C1, int K1,
    const float* __restrict__ W2, const float* __restrict__ bias2,
    const unsigned short* __restrict__ A2, float* __restrict__ C2, int K2) {
  bool sec = blockIdx.x >= 96;
  const float* W = sec ? W2 : W1;
  const float* bias = sec ? bias2 : bias1;
  const unsigned short* A = sec ? A2 : A1;
  float* C = sec ? C2 : C1;
  int K = sec ? K2 : K1;
  int blk = sec ? blockIdx.x - 96 : blockIdx.x;

  int tid = threadIdx.x;
  int wv = tid >> 6, lane = tid & 63;
  int mrow = lane & 15, qd = lane >> 4;
  int j = blk * 16 + mrow;
  const unsigned short* ap = A + (size_t)(wv * 16 + mrow) * K + qd * 8;
  const float* wp = W + (size_t)j * K + qd * 8;
  f32x4 acc = (f32x4){0.f, 0.f, 0.f, 0.f};
  for (int k0 = 0; k0 < K; k0 += 32) {
    bf16x8 af = __builtin_bit_cast(bf16x8, *(const U4*)(ap + k0));
    f32x4 w0 = *(const f32x4*)(wp + k0);
    f32x4 w1 = *(const f32x4*)(wp + k0 + 4);
    U4 braw;
    braw.x = f2bf_bits(w0.x) | (f2bf_bits(w0.y) << 16);
    braw.y = f2bf_bits(w0.z) | (f2bf_bits(w0.w) << 16);
    braw.z = f2bf_bits(w1.x) | (f2bf_bits(w1.y) << 16);
    braw.w = f2bf_bits(w1.z) | (f2bf_bits(w1.w) << 16);
    bf16x8 bf = __builtin_bit_cast(bf16x8, braw);
    acc = __builtin_amdgcn_mfma_f32_16x16x32_bf16(af, bf, acc, 0, 0, 0);
  }
  float bv = bias[j];
#pragma unroll
  for (int r = 0; r < 4; ++r) {
    int brow = wv * 16 + qd * 4 + r;
    C[(size_t)brow * H3_ + j] = acc[r] + bv;
  }
}

// Output projection: wave owns 16 j-cols x all 64 b-rows (4 MFMAs / W-frag).
// W streamed nontemporal (read-once), converted to bf16 once per block.
// Epilogue additionally emits per-(block,b) partial (max, sum-exp) over its
// 64 j-columns so log-softmax needs no extra full read pass.
__global__ __launch_bounds__(256) void k_out(
    const float* __restrict__ W, const float* __restrict__ bias,
    const unsigned short* __restrict__ A, float* __restrict__ C,
    float* __restrict__ pm, float* __restrict__ ps) {
  __shared__ float lmS[4][64], lsS[4][64];
  int tid = threadIdx.x;
  int wv = tid >> 6, lane = tid & 63;
  int mrow = lane & 15, qd = lane >> 4;
  int j = blockIdx.x * 64 + wv * 16 + mrow;
  int jc = j < V_ ? j : V_ - 1;
  const float* wp = W + (size_t)jc * 1024 + qd * 8;
  const unsigned short* ap = A + mrow * 1024 + qd * 8;
  f32x4 acc[4];
#pragma unroll
  for (int r = 0; r < 4; ++r) acc[r] = (f32x4){0.f, 0.f, 0.f, 0.f};
  for (int k0 = 0; k0 < 1024; k0 += 32) {
    f32x4 w0 = ntload4(wp + k0);
    f32x4 w1 = ntload4(wp + k0 + 4);
    U4 braw;
    braw.x = f2bf_bits(w0.x) | (f2bf_bits(w0.y) << 16);
    braw.y = f2bf_bits(w0.z) | (f2bf_bits(w0.w) << 16);
    braw.z = f2bf_bits(w1.x) | (f2bf_bits(w1.y) << 16);
    braw.w = f2bf_bits(w1.z) | (f2bf_bits(w1.w) << 16);
    bf16x8 bw = __builtin_bit_cast(bf16x8, braw);
#pragma unroll
    for (int r = 0; r < 4; ++r) {
      bf16x8 af = __builtin_bit_cast(bf16x8, *(const U4*)(ap + r * 16 * 1024 + k0));
      acc[r] = __builtin_amdgcn_mfma_f32_16x16x32_bf16(af, bw, acc[r], 0, 0, 0);
    }
  }
  float bv = (j < V_) ? bias[j] : 0.f;
  if (j < V_) {
#pragma unroll
    for (int r = 0; r < 4; ++r) {
#pragma unroll
      for (int g = 0; g < 4; ++g) {
        int brow = r * 16 + qd * 4 + g;
        C[(size_t)brow * V_ + j] = acc[r][g] + bv;
      }
    }
  }
  // per-b partial (m, s) over this block's 64 j: reduce across the 16 mrow
  // lanes holding the same b-row (xor offsets 1,2,4,8 stay within qd group),
  // merge 4 waves in LDS. Invalid j uses -1e30 sentinel (finite: no NaN).
#pragma unroll
  for (int r = 0; r < 4; ++r) {
#pragma unroll
    for (int g = 0; g < 4; ++g) {
      float v = (j < V_) ? acc[r][g] + bv : -1e30f;
      float mm = v;
#pragma unroll
      for (int off = 1; off <= 8; off <<= 1)
        mm = fmaxf(mm, __shfl_xor(mm, off, 64));
      float se = __expf(v - mm);
#pragma unroll
      for (int off = 1; off <= 8; off <<= 1)
        se += __shfl_xor(se, off, 64);
      if (mrow == 0) {
        int brow = r * 16 + qd * 4 + g;
        lmS[wv][brow] = mm;
        lsS[wv][brow] = se;
      }
    }
  }
  __syncthreads();
  if (tid < 64) {
    float m = lmS[0][tid], s = lsS[0][tid];
#pragma unroll
    for (int w = 1; w < 4; ++w) {
      float mk = lmS[w][tid], sk = lsS[w][tid];
      float mn = fmaxf(m, mk);
      s = s * __expf(m - mn) + sk * __expf(mk - mn);
      m = mn;
    }
    pm[(size_t)tid * NBLK_OUT + blockIdx.x] = m;
    ps[(size_t)tid * NBLK_OUT + blockIdx.x] = s;
  }
}

// GRU gate combine. Optionally builds out_in bf16 = [h_new | context].
__global__ __launch_bounds__(512) void k_gru(
    const float* __restrict__ gx, const float* __restrict__ gh,
    const float* __restrict__ hprev, float* __restrict__ hnew_out,
    unsigned short* __restrict__ hnew_bf, const float* __restrict__ ctx,
    unsigned short* __restrict__ outin) {
  int b = blockIdx.x, i = threadIdx.x;
  size_t g0 = (size_t)b * H3_ + i;
  float xr = gx[g0], xz = gx[g0 + 512], xn = gx[g0 + 1024];
  float hr = gh[g0], hz = gh[g0 + 512], hn = gh[g0 + 1024];
  float r  = 1.f / (1.f + __expf(-(xr + hr)));
  float z  = 1.f / (1.f + __expf(-(xz + hz)));
  float nn = tanhf(xn + r * hn);
  float hp = hprev[b * H_ + i];
  float h  = (1.f - z) * nn + z * hp;
  hnew_out[b * H_ + i] = h;
  hnew_bf[b * H_ + i]  = (unsigned short)f2bf_bits(h);
  if (outin) {
    outin[b * 1024 + i]       = (unsigned short)f2bf_bits(h);
    outin[b * 1024 + 512 + i] = (unsigned short)f2bf_bits(ctx[b * H_ + i]);
  }
}

// merge 786 per-block (m,s) partials per row -> lse[b]
__global__ __launch_bounds__(256) void k_lse(const float* __restrict__ pm,
                                             const float* __restrict__ ps,
                                             float* __restrict__ lse) {
  __shared__ float rm[4], rs[4];
  int b = blockIdx.x, tid = threadIdx.x, lane = tid & 63, wid = tid >> 6;
  float m = -1e30f, s = 0.f;
  for (int k = tid; k < NBLK_OUT; k += 256) {
    float mk = pm[(size_t)b * NBLK_OUT + k];
    float sk = ps[(size_t)b * NBLK_OUT + k];
    float mn = fmaxf(m, mk);
    s = s * __expf(m - mn) + sk * __expf(mk - mn);
    m = mn;
  }
#pragma unroll
  for (int off = 32; off > 0; off >>= 1) {
    float mo = __shfl_xor(m, off, 64);
    float so = __shfl_xor(s, off, 64);
    float mn = fmaxf(m, mo);
    s = s * __expf(m - mn) + so * __expf(mo - mn);
    m = mn;
  }
  if (lane == 0) { rm[wid] = m; rs[wid] = s; }
  __syncthreads();
  if (tid == 0) {
    float mg = rm[0], sg = rs[0];
    for (int w = 1; w < 4; ++w) {
      float mn = fmaxf(mg, rm[w]);
      sg = sg * __expf(mg - mn) + rs[w] * __expf(rm[w] - mn);
      mg = mn;
    }
    lse[b] = mg + logf(sg);
  }
}

// log_probs = logits - lse[b], full-width single pass
__global__ __launch_bounds__(256) void k_wlp(const float* __restrict__ logits,
                                             const float* __restrict__ lse,
                                             float* __restrict__ out) {
  int b = blockIdx.y;
  int j = blockIdx.x * 256 + threadIdx.x;
  if (j < V_) {
    float v = __builtin_nontemporal_load(logits + (size_t)b * V_ + j);
    __builtin_nontemporal_store(v - lse[b], out + (size_t)b * V_ + j);
  }
}

extern "C" void kernel_launch(void* const* d_in, const int* in_sizes, int n_in,
                              void* d_out, int out_size, void* d_ws, size_t ws_size,
                              hipStream_t stream) {
  const int*   ids    = (const int*)d_in[0];
  const float* hidden = (const float*)d_in[1];
  const float* baw    = (const float*)d_in[2];
  const float* eo     = (const float*)d_in[3];
  const float* emb    = (const float*)d_in[5];
  const float* attn_W = (const float*)d_in[6];
  const float* attn_b = (const float*)d_in[7];
  const float* W_ih0  = (const float*)d_in[8];
  const float* W_hh0  = (const float*)d_in[9];
  const float* b_ih0  = (const float*)d_in[10];
  const float* b_hh0  = (const float*)d_in[11];
  const float* W_ih1  = (const float*)d_in[12];
  const float* W_hh1  = (const float*)d_in[13];
  const float* b_ih1  = (const float*)d_in[14];
  const float* b_hh1  = (const float*)d_in[15];
  const float* out_W  = (const float*)d_in[16];
  const float* out_b  = (const float*)d_in[17];
  float* out = (float*)d_out;

  char* ws = (char*)d_ws;
  float*          q      = (float*)(ws + 0);          //  64*512 f32
  float*          bc     = (float*)(ws + 131072);     //  64*32*512 f32
  float*          ctx    = (float*)(ws + 4325376);    //  64*512 f32
  unsigned short* xcatb  = (unsigned short*)(ws + 4456448);  // 64*1024 bf16
  unsigned short* h0b    = (unsigned short*)(ws + 4587520);  // 64*512
  unsigned short* h1b    = (unsigned short*)(ws + 4653056);  // 64*512
  unsigned short* h0nb   = (unsigned short*)(ws + 4718592);  // 64*512
  unsigned short* outinb = (unsigned short*)(ws + 4784128);  // 64*1024
  float*          gx     = (float*)(ws + 4915200);    // 64*1536 f32
  float*          gh     = (float*)(ws + 5308416);    // 64*1536 f32
  float*          logits = (float*)(ws + 5701632);    // 64*50257 f32
  float*          pm     = (float*)(ws + 18567424);   // 64*786 f32
  float*          ps     = (float*)(ws + 18768640);   // 64*786 f32
  float*          lse    = (float*)(ws + 18969856);   // 64 f32

  float* out_lp   = out;
  float* out_nh   = out + 3216448;
  float* out_ctx  = out + 3281984;
  float* out_attw = out + 3314752;

  k_q   <<<dim3(4, 16), 128, 0, stream>>>(hidden, attn_W, q);
  k_attn<<<2048, 512, 0, stream>>>(eo, hidden, attn_b, q, bc, out_attw);
  k_prep<<<64, 512, 0, stream>>>(ids, hidden, baw, emb, bc, ctx, xcatb, h0b, h1b, out_ctx);

  k_mv2<<<192, 256, 0, stream>>>(W_ih0, b_ih0, xcatb, gx, 1024,
                                 W_hh0, b_hh0, h0b,   gh, 512);
  k_gru<<<64, 512, 0, stream>>>(gx, gh, hidden, out_nh, h0nb,
                                (const float*)nullptr, (unsigned short*)nullptr);

  k_mv2<<<192, 256, 0, stream>>>(W_ih1, b_ih1, h0nb, gx, 512,
                                 W_hh1, b_hh1, h1b,  gh, 512);
  k_gru<<<64, 512, 0, stream>>>(gx, gh, hidden + B_ * H_, out_nh + B_ * H_, h0nb,
                                ctx, outinb);

  k_out<<<NBLK_OUT, 256, 0, stream>>>(out_W, out_b, outinb, logits, pm, ps);
  k_lse<<<64, 256, 0, stream>>>(pm, ps, lse);
  k_wlp<<<dim3(197, 64), 256, 0, stream>>>(logits, lse, out_lp);
}